// Round 7
// baseline (5526.907 us; speedup 1.0000x reference)
//
#include <hip/hip_runtime.h>
#include <stdint.h>

// LSTM final-h. B=128, T=1024, I=256, H=512. Inputs fp32, output fp32.
// R14 = R13 resubmit (container infra failure, no counters). Only change:
// poll guard 1<<26 -> 1<<22 so any unexpected stall fails loud in ~0.3s
// instead of risking a container-level timeout.
// R13 theory: use ALL 256 CUs. R12 (5.08ms, 4.86us/step) ran 128 blocks
// x 512thr -> only 128 CUs populated. Now:
//  - 256 blocks x 256 threads (4 waves). Block owns 16 units x 4 gates;
//    8 domains x 32 blocks x 16 rows. Per-SIMD MFMA and per-block VALU
//    halve; protocol latency terms unchanged. Broadcast 4->8 MB/step.
//  - release reordered: h-store drain moved to TOP of next iter as a
//    counted vmcnt(4) AFTER the x-part MFMAs -> store-ack shadow absorbs
//    the x work; flag posts at the same absolute time.
//  - x fp32->bf16 via v_cvt_pk_bf16_f32 (HW RNE, same rounding as f2b).
//  - 3 independent MFMA accumulator streams (accm/accc1/accc2).
// Invariants kept: zero cache-maintenance ops; h stores WT sc0 sc1;
// h stage loads LLC-direct sc0 sc1; fragment-ordered LDS (0 conflicts);
// per-wave flags + wave0 poll + 2 barriers/step.
// Numerics: same MFMA terms; only fp32 accumulator grouping changed.

#define Bsz 128
#define Tsz 1024
#define Isz 256
#define Hsz 512
#define NBLK 256      // 8 domains x 32 blocks
#define NTHREADS 256  // 4 waves

typedef __attribute__((ext_vector_type(8))) short short8;
typedef __attribute__((ext_vector_type(4))) float float4v;
typedef __attribute__((ext_vector_type(4))) unsigned int uint4v;
typedef __attribute__((ext_vector_type(2))) unsigned int uint2v;

__device__ __forceinline__ float b2f(unsigned short u) {
  union { float f; unsigned int i; } v; v.i = ((unsigned int)u) << 16; return v.f;
}
__device__ __forceinline__ unsigned short f2b(float f) {
  unsigned int u = __float_as_uint(f);
  return (unsigned short)((u + 0x7fffu + ((u >> 16) & 1u)) >> 16);
}
__device__ __forceinline__ float sigmf(float x) { return 1.0f / (1.0f + __expf(-x)); }
__device__ __forceinline__ float tanhf_fast(float x) {
  float e = __expf(-2.0f * fabsf(x));
  float t = (1.0f - e) / (1.0f + e);
  return copysignf(t, x);
}
__device__ __forceinline__ short8 cvt8r(float4v u, float4v v) {
  short8 r;
  r[0] = (short)f2b(u[0]); r[1] = (short)f2b(u[1]);
  r[2] = (short)f2b(u[2]); r[3] = (short)f2b(u[3]);
  r[4] = (short)f2b(v[0]); r[5] = (short)f2b(v[1]);
  r[6] = (short)f2b(v[2]); r[7] = (short)f2b(v[3]);
  return r;
}
// HW packed fp32->bf16 (RNE, same rounding as f2b). No builtin on gfx950.
__device__ __forceinline__ unsigned int cvtpk(float a, float b) {
  unsigned int r;
  asm("v_cvt_pk_bf16_f32 %0, %1, %2" : "=v"(r) : "v"(a), "v"(b));
  return r;
}
__device__ __forceinline__ short8 cvt8pk(float4v u, float4v v) {
  union { unsigned int d[4]; short8 s; } r;
  r.d[0] = cvtpk(u[0], u[1]);
  r.d[1] = cvtpk(u[2], u[3]);
  r.d[2] = cvtpk(v[0], v[1]);
  r.d[3] = cvtpk(v[2], v[3]);
  return r.s;
}

#define MFMA(A, B, C) __builtin_amdgcn_mfma_f32_16x16x32_bf16((A), (B), (C), 0, 0, 0)

// LLC-direct 16B load (coherent h path; bypass L1/L2).
#define LLD(dst, base, OFFB)                                              \
  asm volatile("global_load_dwordx4 %0, %1, off offset:" OFFB " sc0 sc1"  \
               : "=v"(dst) : "v"(base))
// Cached 16B load, pinned at issue point (x prefetch).
#define XLD(dst, base, OFFB)                                              \
  asm volatile("global_load_dwordx4 %0, %1, off offset:" OFFB             \
               : "=v"(dst) : "v"(base))
#define VMW(N)                                                            \
  do { asm volatile("s_waitcnt vmcnt(" #N ")" ::: "memory");              \
       __builtin_amdgcn_sched_barrier(0); } while (0)

// unpack 8 packed dwords (hi|lo<<16) -> one hi frag + one lo frag for kq=q
#define UNPACK_Q(q, dA, dB) do {                                          \
    short8 h8, l8;                                                        \
    h8[0]=(short)(dA[0]&0xffffu); l8[0]=(short)(dA[0]>>16);               \
    h8[1]=(short)(dA[1]&0xffffu); l8[1]=(short)(dA[1]>>16);               \
    h8[2]=(short)(dA[2]&0xffffu); l8[2]=(short)(dA[2]>>16);               \
    h8[3]=(short)(dA[3]&0xffffu); l8[3]=(short)(dA[3]>>16);               \
    h8[4]=(short)(dB[0]&0xffffu); l8[4]=(short)(dB[0]>>16);               \
    h8[5]=(short)(dB[1]&0xffffu); l8[5]=(short)(dB[1]>>16);               \
    h8[6]=(short)(dB[2]&0xffffu); l8[6]=(short)(dB[2]>>16);               \
    h8[7]=(short)(dB[3]&0xffffu); l8[7]=(short)(dB[3]>>16);               \
    hhi_pl[fh + (q) * 16] = h8;                                           \
    hlo_pl[fh + (q) * 16] = l8;                                           \
  } while (0)

__global__ __launch_bounds__(NTHREADS, 1) void lstm_persistent(
    const float* __restrict__ x,
    const float* __restrict__ wih,
    const float* __restrict__ whh,
    const float* __restrict__ bih,
    const float* __restrict__ bhh,
    float* __restrict__ out,
    unsigned int* __restrict__ hb0,     // h packed (hi | lo<<16), parity 0: [128][512] dwords
    unsigned int* __restrict__ hb1,     // parity 1
    unsigned int* __restrict__ flags)   // 8 domains x (32 blocks x 256B chunk: 4 wave-dwords)
{
  __shared__ short8 hhi_pl[1024];      // 16 KB: h hi fragments, f = ks*64+kq*16+row
  __shared__ short8 hlo_pl[1024];      // 16 KB: h lo fragments
  __shared__ short8 x_pl[2][512];      // 16 KB: x fragments, double-buffered

  const int tid  = threadIdx.x;
  const int wid  = tid >> 6;
  const int lane = tid & 63;
  const int l15  = lane & 15;
  const int kq   = lane >> 4;
  const int qg   = l15 >> 2;   // gate index 0..3 (i,f,g,o)
  const int ug   = l15 & 3;    // unit-within-4
  const int blk  = blockIdx.x;
  const int dom  = blk >> 5;   // 8 domains (16 batch rows each)
  const int bi   = blk & 31;   // block-in-domain: units bi*16 .. bi*16+15
  const int col  = qg * Hsz + bi * 16 + wid * 4 + ug;  // gate column
  const int rowbase = dom * 16;

  // ---- W into registers as B-fragments (one-time prologue) ----
  short8 wx[8], whhhi[16], whhlo[16];
  {
    const float* p = wih + (size_t)col * Isz + kq * 8;
#pragma unroll
    for (int ks = 0; ks < 8; ++ks) {
      float4v u0 = *(const float4v*)(p + ks * 32);
      float4v u1 = *(const float4v*)(p + ks * 32 + 4);
      wx[ks] = cvt8r(u0, u1);
    }
  }
  {
    const float* p = whh + (size_t)col * Hsz + kq * 8;
#pragma unroll
    for (int ks = 0; ks < 16; ++ks) {
      float4v u0 = *(const float4v*)(p + ks * 32);
      float4v u1 = *(const float4v*)(p + ks * 32 + 4);
      short8 hi = cvt8r(u0, u1);
      short8 lo;
#pragma unroll
      for (int e = 0; e < 4; ++e) {
        lo[e]     = (short)f2b(u0[e] - b2f((unsigned short)hi[e]));
        lo[e + 4] = (short)f2b(u1[e] - b2f((unsigned short)hi[e + 4]));
      }
      whhhi[ks] = hi; whhlo[ks] = lo;
    }
  }
  const float biasC = bih[col] + bhh[col];

  // flags: dom*2048 + bi*64 + wid (dwords); 256B chunk per block
  unsigned int* myf = flags + dom * 2048 + bi * 64 + wid;
  const unsigned int* pollp = flags + dom * 2048 + (lane >> 1) * 64 + (lane & 1) * 2;

  // ---- staging maps (fragment-ordered, conflict-free both sides) ----
  const int srow = tid & 15;            // local row this thread stages
  const int grow = rowbase + srow;      // global row
  const int cidx = tid >> 4;            // 0..15: 32-unit K-chunk (= ks for h)
  const int fh   = cidx * 64 + srow;                              // h frag base (+q*16)
  const int fx   = (cidx >> 1) * 64 + (cidx & 1) * 32 + srow;     // x frag base (+j*16)
  const float* xsrc0 = x + (size_t)grow * (Tsz * Isz) + cidx * 16;

  // ---- prologue: stage x(0) ----
  {
    float4v u0, u1, u2, u3;
    XLD(u0, xsrc0, "0");  XLD(u1, xsrc0, "16");
    XLD(u2, xsrc0, "32"); XLD(u3, xsrc0, "48");
    VMW(0);
    x_pl[0][fx]      = cvt8pk(u0, u1);
    x_pl[0][fx + 16] = cvt8pk(u2, u3);
  }
  __syncthreads();

  float cstv = 0.f;                              // cell state: row kq*4+qg, unit ug
  const int growo = rowbase + kq * 4 + qg;       // output row this lane owns
  const int hunit = bi * 16 + wid * 4 + ug;      // output unit this lane owns

  for (int t = 0; t < Tsz; ++t) {
    const int par = t & 1;

    // ---- issue x(t+1) prefetch (retires during poll/stage) ----
    float4v xu0, xu1, xu2, xu3;
    const int tn = (t + 1 < Tsz) ? t + 1 : t;
    {
      const float* xp = xsrc0 + (size_t)tn * Isz;
      XLD(xu0, xp, "0");  XLD(xu1, xp, "16");
      XLD(xu2, xp, "32"); XLD(xu3, xp, "48");
    }

    // ---- x-part MFMAs (2 streams; fills the h-store ack shadow) ----
    float4v accm  = {0.f, 0.f, 0.f, 0.f};
    float4v accc1 = {0.f, 0.f, 0.f, 0.f};
    float4v accc2 = {0.f, 0.f, 0.f, 0.f};
#pragma unroll
    for (int ks = 0; ks < 8; ks += 2) {
      short8 xa0 = x_pl[par][ks * 64 + lane];
      short8 xa1 = x_pl[par][(ks + 1) * 64 + lane];
      accm  = MFMA(xa0, wx[ks], accm);
      accc1 = MFMA(xa1, wx[ks + 1], accc1);
    }

    // ---- deferred release for h(t) (stores issued end of prev iter):
    // counted drain leaves the 4 fresh x loads in flight; store ack has
    // been progressing under the x MFMAs. Then flag, then poll. ----
    if (t > 0) {
      VMW(4);
      if (lane == 0) {
        unsigned int fv = (unsigned)t;
        asm volatile("global_store_dword %0, %1, off sc0 sc1"
                     :: "v"(myf), "v"(fv) : "memory");
      }
      if (wid == 0) {
        int guard = 0;
        for (;;) {
          uint2v fv;
          asm volatile("global_load_dwordx2 %0, %1, off sc0 sc1\n\t"
                       "s_waitcnt vmcnt(0)"
                       : "=v"(fv) : "v"(pollp) : "memory");
          unsigned m = fv[0] < fv[1] ? fv[0] : fv[1];
          if (__all(m >= (unsigned)t)) break;
          __builtin_amdgcn_s_sleep(1);
          if (++guard > (1 << 22)) break;  // fail loud in ~0.3s, never hang
        }
      }
    }
    __syncthreads();  // barrier1: h(t) globally visible; LDS planes reusable

    // ---- issue h(t) stage loads: 32 units (128B) of one row per thread ----
    const unsigned int* hsrc =
        (par ? hb1 : hb0) + (size_t)grow * Hsz + cidx * 32;
    uint4v d0, d1, d2, d3, d4, d5, d6, d7;
    LLD(d0, hsrc, "0");  LLD(d1, hsrc, "16");
    LLD(d2, hsrc, "32"); LLD(d3, hsrc, "48");
    LLD(d4, hsrc, "64"); LLD(d5, hsrc, "80");
    LLD(d6, hsrc, "96"); LLD(d7, hsrc, "112");

    // x loads (older in FIFO) retired once <=8 outstanding: write x plane
    VMW(8);
    if (t + 1 < Tsz) {
      x_pl[par ^ 1][fx]      = cvt8pk(xu0, xu1);
      x_pl[par ^ 1][fx + 16] = cvt8pk(xu2, xu3);
    }

    // h loads done: unpack into fragment planes (lane-contiguous writes)
    VMW(0);
    UNPACK_Q(0, d0, d1);
    UNPACK_Q(1, d2, d3);
    UNPACK_Q(2, d4, d5);
    UNPACK_Q(3, d6, d7);
    __syncthreads();  // barrier2: planes ready

    // ---- h-part MFMAs (W in regs, 3 independent streams) ----
#pragma unroll
    for (int ks = 0; ks < 16; ++ks) {
      short8 ha = hhi_pl[ks * 64 + lane];
      short8 la = hlo_pl[ks * 64 + lane];
      accm  = MFMA(ha, whhhi[ks], accm);
      accc1 = MFMA(ha, whhlo[ks], accc1);
      accc2 = MFMA(la, whhhi[ks], accc2);
    }

    // ---- gates on ALL lanes: lane owns (row kq*4+qg, unit ug) ----
    float v0 = (accm[0] + accc1[0]) + accc2[0] + biasC;
    float v1 = (accm[1] + accc1[1]) + accc2[1] + biasC;
    float v2 = (accm[2] + accc1[2]) + accc2[2] + biasC;
    float v3 = (accm[3] + accc1[3]) + accc2[3] + biasC;
    // send v[qg^m] on exchange xor(4m); receive partner's row-qg gate
    int k1 = qg ^ 1, k2 = qg ^ 2, k3 = qg ^ 3;
    float s0 = (qg == 0) ? v0 : (qg == 1) ? v1 : (qg == 2) ? v2 : v3;
    float s1 = (k1 == 0) ? v0 : (k1 == 1) ? v1 : (k1 == 2) ? v2 : v3;
    float s2 = (k2 == 0) ? v0 : (k2 == 1) ? v1 : (k2 == 2) ? v2 : v3;
    float s3 = (k3 == 0) ? v0 : (k3 == 1) ? v1 : (k3 == 2) ? v2 : v3;
    float r4  = __shfl_xor(s1, 4, 64);   // gate qg^1, row qg
    float r8  = __shfl_xor(s2, 8, 64);   // gate qg^2, row qg
    float r12 = __shfl_xor(s3, 12, 64);  // gate qg^3, row qg
    float gi = (qg == 0) ? s0 : (qg == 1) ? r4 : (qg == 2) ? r8 : r12;
    float gf = (qg == 1) ? s0 : (qg == 0) ? r4 : (qg == 3) ? r8 : r12;
    float gG = (qg == 2) ? s0 : (qg == 3) ? r4 : (qg == 0) ? r8 : r12;
    float go = (qg == 3) ? s0 : (qg == 2) ? r4 : (qg == 1) ? r8 : r12;

    float ig = sigmf(gi);
    float fg = sigmf(gf);
    float gg = tanhf_fast(gG);
    float og = sigmf(go);
    float c  = fg * cstv + ig * gg;
    cstv = c;
    float hv = og * tanhf_fast(c);

    if (t == Tsz - 1) {
      out[(size_t)growo * Hsz + hunit] = hv;     // fp32 output
    } else {
      unsigned short hi16 = f2b(hv);
      unsigned short lo16 = f2b(hv - b2f(hi16));
      unsigned int pk = (unsigned int)hi16 | ((unsigned int)lo16 << 16);
      unsigned int* pp = (par ? hb0 : hb1) + (size_t)growo * Hsz + hunit;
      asm volatile("global_store_dword %0, %1, off sc0 sc1"
                   :: "v"(pp), "v"(pk) : "memory");
      // no drain here: next iteration's top VMW(4) + flag handles release,
      // with the store ack progressing under the x-part MFMAs.
    }
  }
}

extern "C" void kernel_launch(void* const* d_in, const int* in_sizes, int n_in,
                              void* d_out, int out_size, void* d_ws, size_t ws_size,
                              hipStream_t stream) {
  if (n_in < 5) return;
  long long s0 = in_sizes[0], s1 = in_sizes[1], s2 = in_sizes[2],
            s3 = in_sizes[3], s4 = in_sizes[4];
  if (!(s1 > 0 && s3 > 0 && s0 == 64 * s1 && s2 == 2 * s1 &&
        s1 == 256 * s3 && s3 == s4)) return;

  const float* x   = (const float*)d_in[0];
  const float* wih = (const float*)d_in[1];
  const float* whh = (const float*)d_in[2];
  const float* bih = (const float*)d_in[3];
  const float* bhh = (const float*)d_in[4];
  float* out = (float*)d_out;

  char* ws = (char*)d_ws;
  const size_t FLAGS_BYTES = 8 * 2048 * 4;         // 64 KB (8 domains x 32 x 256B)
  const size_t HB = (size_t)Bsz * Hsz * 4;         // 256 KB per packed h buffer
  unsigned int* flags = (unsigned int*)ws;
  unsigned int* hb0 = (unsigned int*)(ws + FLAGS_BYTES);
  unsigned int* hb1 = (unsigned int*)(ws + FLAGS_BYTES + HB);

  hipMemsetAsync(d_ws, 0, FLAGS_BYTES + 2 * HB, stream);

  hipLaunchKernelGGL(lstm_persistent, dim3(NBLK), dim3(NTHREADS), 0, stream,
                     x, wih, whh, bih, bhh, out, hb0, hb1, flags);
}

// Round 8
// 5323.959 us; speedup vs baseline: 1.0381x; 1.0381x over previous
//
#include <hip/hip_runtime.h>
#include <stdint.h>

// LSTM final-h. B=128, T=1024, I=256, H=512. Inputs fp32, output fp32.
// R15: parity-tagged h (flag-free sync), R12 geometry.
// R14 falsified the all-CU theory (256 blocks: 5.53ms > R12's 5.08ms with
// half the per-CU work) => step time is a fixed serial latency chain:
// gates -> h-store ack -> flag store -> flag poll -> h load -> MFMA
// (~4 serial LLC transactions + 2 barriers). Now the freshness bit rides
// IN the data: packed h dword = hi16 | lo16<<16, and lo's LSB (~2^-15
// relative, invisible at absmax 1.95e-3) is an epoch tag:
//   h(t) lives in buffer t&1 with tag (t>>1)&1 in every dword.
//   hb0 memset 0x00 (h(0)=0, tag 0); hb1 memset 0x01 (virgin tag 1, so
//   t=1's expected tag 0 can't match stale init).
// Consumer polls its OWN 64B chunk LLC-direct and checks 16 tag bits;
// dword stores are atomic => tag match == dword fresh. Deletes: producer
// store-ack drain, flag store, flag poll round trip. Double-buffered h
// LDS planes (80KB total) remove one of the two barriers: per step =
// one tag-poll + ONE __syncthreads.
// Invariants: zero cache-maintenance ops; WT sc0 sc1 h stores; LLC-direct
// sc0 sc1 stage loads; fragment-ordered LDS (0 bank conflicts).
// Numerics: identical MFMA terms/order as R12; lo LSB tag adds ~2^-15
// relative perturbation (absmax unchanged at 1.95e-3 scale).

#define Bsz 128
#define Tsz 1024
#define Isz 256
#define Hsz 512
#define NBLK 128      // 8 domains x 16 blocks
#define NTHREADS 512  // 8 waves

typedef __attribute__((ext_vector_type(8))) short short8;
typedef __attribute__((ext_vector_type(4))) float float4v;
typedef __attribute__((ext_vector_type(4))) unsigned int uint4v;

__device__ __forceinline__ float b2f(unsigned short u) {
  union { float f; unsigned int i; } v; v.i = ((unsigned int)u) << 16; return v.f;
}
__device__ __forceinline__ unsigned short f2b(float f) {
  unsigned int u = __float_as_uint(f);
  return (unsigned short)((u + 0x7fffu + ((u >> 16) & 1u)) >> 16);
}
__device__ __forceinline__ float sigmf(float x) { return 1.0f / (1.0f + __expf(-x)); }
__device__ __forceinline__ float tanhf_fast(float x) {
  float e = __expf(-2.0f * fabsf(x));
  float t = (1.0f - e) / (1.0f + e);
  return copysignf(t, x);
}
__device__ __forceinline__ short8 cvt8r(float4v u, float4v v) {
  short8 r;
  r[0] = (short)f2b(u[0]); r[1] = (short)f2b(u[1]);
  r[2] = (short)f2b(u[2]); r[3] = (short)f2b(u[3]);
  r[4] = (short)f2b(v[0]); r[5] = (short)f2b(v[1]);
  r[6] = (short)f2b(v[2]); r[7] = (short)f2b(v[3]);
  return r;
}
// HW packed fp32->bf16 (RNE, same rounding as f2b). No builtin on gfx950.
__device__ __forceinline__ unsigned int cvtpk(float a, float b) {
  unsigned int r;
  asm("v_cvt_pk_bf16_f32 %0, %1, %2" : "=v"(r) : "v"(a), "v"(b));
  return r;
}
__device__ __forceinline__ short8 cvt8pk(float4v u, float4v v) {
  union { unsigned int d[4]; short8 s; } r;
  r.d[0] = cvtpk(u[0], u[1]);
  r.d[1] = cvtpk(u[2], u[3]);
  r.d[2] = cvtpk(v[0], v[1]);
  r.d[3] = cvtpk(v[2], v[3]);
  return r.s;
}

#define MFMA(A, B, C) __builtin_amdgcn_mfma_f32_16x16x32_bf16((A), (B), (C), 0, 0, 0)

// LLC-direct 16B load (coherent h path; bypass L1/L2).
#define LLD(dst, base, OFFB)                                              \
  asm volatile("global_load_dwordx4 %0, %1, off offset:" OFFB " sc0 sc1"  \
               : "=v"(dst) : "v"(base))
// Cached 16B load, pinned at issue point (x prefetch).
#define XLD(dst, base, OFFB)                                              \
  asm volatile("global_load_dwordx4 %0, %1, off offset:" OFFB             \
               : "=v"(dst) : "v"(base))
#define VMW(N)                                                            \
  do { asm volatile("s_waitcnt vmcnt(" #N ")" ::: "memory");              \
       __builtin_amdgcn_sched_barrier(0); } while (0)

__global__ __launch_bounds__(NTHREADS, 2) void lstm_persistent(
    const float* __restrict__ x,
    const float* __restrict__ wih,
    const float* __restrict__ whh,
    const float* __restrict__ bih,
    const float* __restrict__ bhh,
    float* __restrict__ out,
    unsigned int* __restrict__ hb0,     // h packed (hi | lo<<16) + tag, parity 0
    unsigned int* __restrict__ hb1)     // parity 1 (init 0x01 bytes: tag 1)
{
  __shared__ short8 hhi_pl[2][1024];   // 32 KB: h hi fragments, dbuf by t&1
  __shared__ short8 hlo_pl[2][1024];   // 32 KB: h lo fragments
  __shared__ short8 x_pl[2][512];      // 16 KB: x fragments, dbuf

  const int tid  = threadIdx.x;
  const int wid  = tid >> 6;
  const int lane = tid & 63;
  const int l15  = lane & 15;
  const int kq   = lane >> 4;
  const int qg   = l15 >> 2;   // gate index 0..3 (i,f,g,o)
  const int ug   = l15 & 3;    // unit-within-4
  const int blk  = blockIdx.x;
  const int dom  = blk >> 4;   // 8 domains (16 batch rows each)
  const int bi   = blk & 15;   // block-in-domain: units bi*32 .. bi*32+31
  const int col  = qg * Hsz + bi * 32 + wid * 4 + ug;  // gate column
  const int rowbase = dom * 16;

  // ---- W into registers as B-fragments (one-time prologue) ----
  short8 wx[8], whhhi[16], whhlo[16];
  {
    const float* p = wih + (size_t)col * Isz + kq * 8;
#pragma unroll
    for (int ks = 0; ks < 8; ++ks) {
      float4v u0 = *(const float4v*)(p + ks * 32);
      float4v u1 = *(const float4v*)(p + ks * 32 + 4);
      wx[ks] = cvt8r(u0, u1);
    }
  }
  {
    const float* p = whh + (size_t)col * Hsz + kq * 8;
#pragma unroll
    for (int ks = 0; ks < 16; ++ks) {
      float4v u0 = *(const float4v*)(p + ks * 32);
      float4v u1 = *(const float4v*)(p + ks * 32 + 4);
      short8 hi = cvt8r(u0, u1);
      short8 lo;
#pragma unroll
      for (int e = 0; e < 4; ++e) {
        lo[e]     = (short)f2b(u0[e] - b2f((unsigned short)hi[e]));
        lo[e + 4] = (short)f2b(u1[e] - b2f((unsigned short)hi[e + 4]));
      }
      whhhi[ks] = hi; whhlo[ks] = lo;
    }
  }
  const float biasC = bih[col] + bhh[col];

  // ---- staging maps (fragment-ordered, conflict-free both sides) ----
  const int srow = tid & 15;            // local row this thread stages
  const int grow = rowbase + srow;      // global row
  const int cidx = tid >> 4;            // 0..31: 16-dword (64B) chunk index
  const int f1   = (cidx >> 1) * 64 + (cidx & 1) * 32 + srow;  // frag; also f1+16
  const float* xsrc0 = x + (size_t)grow * (Tsz * Isz) + cidx * 8;

  // ---- prologue: stage x(0) ----
  {
    float4v u0, u1;
    XLD(u0, xsrc0, "0"); XLD(u1, xsrc0, "16");
    VMW(0);
    x_pl[0][tid] = cvt8pk(u0, u1);
  }
  __syncthreads();

  float cstv = 0.f;                              // cell state: row kq*4+qg, unit ug
  const int growo = rowbase + kq * 4 + qg;       // output row this lane owns
  const int hunit = bi * 32 + wid * 4 + ug;      // output unit this lane owns

  for (int t = 0; t < Tsz; ++t) {
    const int par = t & 1;

    // ---- issue x(t+1) prefetch (retires under the tag-poll) ----
    float4v xu0, xu1;
    const int tn = (t + 1 < Tsz) ? t + 1 : t;
    {
      const float* xp = xsrc0 + (size_t)tn * Isz;
      XLD(xu0, xp, "0"); XLD(xu1, xp, "16");
    }

    // ---- x-part MFMAs (overlap producers' store flight time) ----
    float4v accm = {0.f, 0.f, 0.f, 0.f};
    float4v accc = {0.f, 0.f, 0.f, 0.f};
#pragma unroll
    for (int ks = 0; ks < 8; ++ks) {
      short8 xa = x_pl[par][ks * 64 + lane];
      accm = MFMA(xa, wx[ks], accm);
    }

    // ---- tag-poll own 64B h chunk (freshness rides in the data) ----
    const unsigned int* hsrc =
        (par ? hb1 : hb0) + (size_t)grow * Hsz + cidx * 16;
    const unsigned int tagm = ((unsigned int)((t >> 1) & 1)) << 16;
    uint4v d0, d1, d2, d3;
    {
      int guard = 0;
      for (;;) {
        LLD(d0, hsrc, "0");  LLD(d1, hsrc, "16");
        LLD(d2, hsrc, "32"); LLD(d3, hsrc, "48");
        VMW(0);   // also drains the 2 x loads (older in FIFO)
        unsigned int a =
            (d0[0] ^ tagm) | (d0[1] ^ tagm) | (d0[2] ^ tagm) | (d0[3] ^ tagm) |
            (d1[0] ^ tagm) | (d1[1] ^ tagm) | (d1[2] ^ tagm) | (d1[3] ^ tagm) |
            (d2[0] ^ tagm) | (d2[1] ^ tagm) | (d2[2] ^ tagm) | (d2[3] ^ tagm) |
            (d3[0] ^ tagm) | (d3[1] ^ tagm) | (d3[2] ^ tagm) | (d3[3] ^ tagm);
        if (!(a & 0x00010000u)) break;     // all 16 tag bits match -> fresh
        __builtin_amdgcn_s_sleep(1);
        if (++guard > (1 << 20)) break;    // fail loud (~0.3s), never hang
      }
    }

    // ---- write next x plane (loads drained by poll) + h planes[par] ----
    if (t + 1 < Tsz) x_pl[par ^ 1][tid] = cvt8pk(xu0, xu1);
    {
      short8 h0, h1, l0, l1;
#pragma unroll
      for (int e = 0; e < 4; ++e) {
        h0[e]     = (short)(d0[e] & 0xffffu); l0[e]     = (short)(d0[e] >> 16);
        h0[e + 4] = (short)(d1[e] & 0xffffu); l0[e + 4] = (short)(d1[e] >> 16);
        h1[e]     = (short)(d2[e] & 0xffffu); l1[e]     = (short)(d2[e] >> 16);
        h1[e + 4] = (short)(d3[e] & 0xffffu); l1[e + 4] = (short)(d3[e] >> 16);
      }
      hhi_pl[par][f1]      = h0;  hlo_pl[par][f1]      = l0;
      hhi_pl[par][f1 + 16] = h1;  hlo_pl[par][f1 + 16] = l1;
    }
    __syncthreads();  // the ONLY barrier: planes ready; prev-iter reads done

    // ---- h-part MFMAs (W in regs, fragment-ordered LDS: 0 conflicts) ----
#pragma unroll
    for (int ks = 0; ks < 16; ++ks) {
      short8 ha = hhi_pl[par][ks * 64 + lane];
      short8 la = hlo_pl[par][ks * 64 + lane];
      accm = MFMA(ha, whhhi[ks], accm);
      accc = MFMA(ha, whhlo[ks], accc);
      accc = MFMA(la, whhhi[ks], accc);
    }

    // ---- gates on ALL lanes: lane owns (row kq*4+qg, unit ug) ----
    float v0 = accm[0] + accc[0] + biasC;
    float v1 = accm[1] + accc[1] + biasC;
    float v2 = accm[2] + accc[2] + biasC;
    float v3 = accm[3] + accc[3] + biasC;
    // send v[qg^m] on exchange xor(4m); receive partner's row-qg gate
    int k1 = qg ^ 1, k2 = qg ^ 2, k3 = qg ^ 3;
    float s0 = (qg == 0) ? v0 : (qg == 1) ? v1 : (qg == 2) ? v2 : v3;
    float s1 = (k1 == 0) ? v0 : (k1 == 1) ? v1 : (k1 == 2) ? v2 : v3;
    float s2 = (k2 == 0) ? v0 : (k2 == 1) ? v1 : (k2 == 2) ? v2 : v3;
    float s3 = (k3 == 0) ? v0 : (k3 == 1) ? v1 : (k3 == 2) ? v2 : v3;
    float r4  = __shfl_xor(s1, 4, 64);   // gate qg^1, row qg
    float r8  = __shfl_xor(s2, 8, 64);   // gate qg^2, row qg
    float r12 = __shfl_xor(s3, 12, 64);  // gate qg^3, row qg
    float gi = (qg == 0) ? s0 : (qg == 1) ? r4 : (qg == 2) ? r8 : r12;
    float gf = (qg == 1) ? s0 : (qg == 0) ? r4 : (qg == 3) ? r8 : r12;
    float gG = (qg == 2) ? s0 : (qg == 3) ? r4 : (qg == 0) ? r8 : r12;
    float go = (qg == 3) ? s0 : (qg == 2) ? r4 : (qg == 1) ? r8 : r12;

    float ig = sigmf(gi);
    float fg = sigmf(gf);
    float gg = tanhf_fast(gG);
    float og = sigmf(go);
    float c  = fg * cstv + ig * gg;
    cstv = c;
    float hv = og * tanhf_fast(c);

    if (t == Tsz - 1) {
      out[(size_t)growo * Hsz + hunit] = hv;     // fp32 output
    } else {
      unsigned short hi16 = f2b(hv);
      unsigned short lo16 = f2b(hv - b2f(hi16));
      // epoch tag in lo's LSB (~2^-15 relative: numerically invisible)
      lo16 = (unsigned short)((lo16 & 0xFFFEu) |
                              ((unsigned int)((t + 1) >> 1) & 1u));
      unsigned int pk = (unsigned int)hi16 | ((unsigned int)lo16 << 16);
      unsigned int* pp = (par ? hb0 : hb1) + (size_t)growo * Hsz + hunit;
      asm volatile("global_store_dword %0, %1, off sc0 sc1"
                   :: "v"(pp), "v"(pk) : "memory");
      // no drain, no flag: consumers detect freshness from the tag itself;
      // the store retires under next iter's poll VMW(0).
    }
  }
}

extern "C" void kernel_launch(void* const* d_in, const int* in_sizes, int n_in,
                              void* d_out, int out_size, void* d_ws, size_t ws_size,
                              hipStream_t stream) {
  if (n_in < 5) return;
  long long s0 = in_sizes[0], s1 = in_sizes[1], s2 = in_sizes[2],
            s3 = in_sizes[3], s4 = in_sizes[4];
  if (!(s1 > 0 && s3 > 0 && s0 == 64 * s1 && s2 == 2 * s1 &&
        s1 == 256 * s3 && s3 == s4)) return;

  const float* x   = (const float*)d_in[0];
  const float* wih = (const float*)d_in[1];
  const float* whh = (const float*)d_in[2];
  const float* bih = (const float*)d_in[3];
  const float* bhh = (const float*)d_in[4];
  float* out = (float*)d_out;

  char* ws = (char*)d_ws;
  const size_t HB = (size_t)Bsz * Hsz * 4;         // 256 KB per packed h buffer
  unsigned int* hb0 = (unsigned int*)ws;
  unsigned int* hb1 = (unsigned int*)(ws + HB);

  // hb0: h(0)=0, tag 0. hb1: 0x01 bytes -> tag 1 (can't collide with
  // h(1)'s expected tag 0), hi/lo ~2^-125 (never read as data anyway).
  hipMemsetAsync(hb0, 0x00, HB, stream);
  hipMemsetAsync(hb1, 0x01, HB, stream);

  hipLaunchKernelGGL(lstm_persistent, dim3(NBLK), dim3(NTHREADS), 0, stream,
                     x, wih, whh, bih, bhh, out, hb0, hb1);
}